// Round 2
// 688.382 us; speedup vs baseline: 1.0715x; 1.0715x over previous
//
#include <hip/hip_runtime.h>
#include <stdint.h>

// Problem constants (from reference)
#define GB   64      // batch
#define GT   1000    // timesteps
#define GIN  512
#define GOUT 512
#define GM   (GB*GT) // 64000 GEMM rows
#define NCH  20      // scan chunks
#define CHL  50      // chunk length (NCH*CHL == GT)

typedef __attribute__((ext_vector_type(8))) __bf16 bf8_t;   // MFMA A/B frag
typedef __attribute__((ext_vector_type(4))) float f4_t;     // MFMA C/D frag
typedef __attribute__((ext_vector_type(8))) unsigned short us8_t;
typedef __attribute__((ext_vector_type(2))) float f2v;
typedef __attribute__((ext_vector_type(4))) float f4v;

typedef __attribute__((address_space(1))) const uint32_t gu32_t;
typedef __attribute__((address_space(3))) uint32_t lu32_t;

static __device__ __forceinline__ unsigned short f2bf(float f) {
    // round-to-nearest-even fp32 -> bf16 bits
    union { float f; unsigned u; } v; v.f = f;
    unsigned r = v.u + 0x7fffu + ((v.u >> 16) & 1u);
    return (unsigned short)(r >> 16);
}

static __device__ __forceinline__ unsigned short f2h(float f) {
    _Float16 h = (_Float16)f;          // v_cvt_f16_f32 (RTN)
    unsigned short s; __builtin_memcpy(&s, &h, 2);
    return s;
}
static __device__ __forceinline__ float lo_h(uint32_t u) {
    unsigned short s = (unsigned short)(u & 0xffffu);
    _Float16 h; __builtin_memcpy(&h, &s, 2);
    return (float)h;
}
static __device__ __forceinline__ float hi_h(uint32_t u) {
    unsigned short s = (unsigned short)(u >> 16);
    _Float16 h; __builtin_memcpy(&h, &s, 2);
    return (float)h;
}
// nontemporal float2 store (write-once output streams: don't pollute L2/L3)
static __device__ __forceinline__ void nts2(float* p, float x, float y) {
    f2v v = {x, y};
    __builtin_nontemporal_store(v, (f2v*)p);
}

// ---------------------------------------------------------------------------
// One-time fp32 -> bf16 conversion of X (32.768M) and W (0.262M).
// Destinations live in the states region of d_out (overwritten only by pass3,
// which runs after the GEMM -- stream order makes this safe).
// Also clears the spike flag (folds the old hipMemsetAsync node in).
// NT loads: X is read-once; keep L3 for Xh/cur.
// ---------------------------------------------------------------------------
#define NX8 4096000   // 32768000/8
#define NW8 32768     // 262144/8
__global__ __launch_bounds__(256) void alif_cvt(
    const float* __restrict__ X, const float* __restrict__ W,
    unsigned short* __restrict__ Xh, unsigned short* __restrict__ Wh,
    unsigned int* __restrict__ flag)
{
    if (blockIdx.x == 0 && threadIdx.x == 0) *flag = 0u;
    const size_t i = (size_t)blockIdx.x * 256 + threadIdx.x;
    const float* src; unsigned short* dst;
    if (i < NX8) { src = X + i * 8; dst = Xh + i * 8; }
    else         { const size_t j = i - NX8; src = W + j * 8; dst = Wh + j * 8; }
    const f4v a = __builtin_nontemporal_load((const f4v*)src);
    const f4v b = __builtin_nontemporal_load((const f4v*)src + 1);
    us8_t r;
    r[0] = f2bf(a.x); r[1] = f2bf(a.y); r[2] = f2bf(a.z); r[3] = f2bf(a.w);
    r[4] = f2bf(b.x); r[5] = f2bf(b.y); r[6] = f2bf(b.z); r[7] = f2bf(b.w);
    *(us8_t*)dst = r;
}

// ---------------------------------------------------------------------------
// cur[m][n] = X[m][k] . W[n][k] + bias[n]  (bf16 inputs)
// 128x128x32 tiles, global_load_lds width-16 staging (m97-style).
// HALF=true: write fp16 cur into workspace (65.5 MB, L3-resident for passes).
// HALF=false: legacy fp32 cur into the zs region of d_out.
// ---------------------------------------------------------------------------
template<bool HALF>
__global__ __launch_bounds__(256) void alif_gemm(
    const unsigned short* __restrict__ Xh, const unsigned short* __restrict__ Wh,
    const float* __restrict__ bias, float* __restrict__ cur,
    unsigned short* __restrict__ curh)
{
    __shared__ unsigned short As[128 * 32];
    __shared__ unsigned short Bs[128 * 32];
    const int tid  = threadIdx.x;
    const int bn   = blockIdx.x & 3;    // N fastest: 4 blocks share one A panel
    const int bm   = blockIdx.x >> 2;   // 0..499
    const int lane = tid & 63;
    const int wave = tid >> 6;
    const int wm   = (wave >> 1) * 64;
    const int wn   = (wave & 1) * 64;
    const int quad = lane >> 4;
    const int l15  = lane & 15;
    const int srow = lane >> 2;
    const int scol = (lane & 3) * 8;

    f4_t acc[4][4];
    #pragma unroll
    for (int i = 0; i < 4; ++i)
        #pragma unroll
        for (int j = 0; j < 4; ++j) acc[i][j] = (f4_t)(0.0f);

    for (int k0 = 0; k0 < GIN; k0 += 32) {
        #pragma unroll
        for (int s = wave; s < 8; s += 4) {
            const int row = s * 16 + srow;
            const unsigned short* ga = Xh + (size_t)(bm * 128 + row) * GIN + k0 + scol;
            const unsigned short* gb = Wh + (size_t)(bn * 128 + row) * GIN + k0 + scol;
            __builtin_amdgcn_global_load_lds((gu32_t*)ga, (lu32_t*)&As[s * 512], 16, 0, 0);
            __builtin_amdgcn_global_load_lds((gu32_t*)gb, (lu32_t*)&Bs[s * 512], 16, 0, 0);
        }
        __syncthreads();
        bf8_t afr[4], bfr[4];
        #pragma unroll
        for (int i = 0; i < 4; ++i) {
            afr[i] = *(const bf8_t*)(&As[(wm + i * 16 + l15) * 32 + quad * 8]);
            bfr[i] = *(const bf8_t*)(&Bs[(wn + i * 16 + l15) * 32 + quad * 8]);
        }
        #pragma unroll
        for (int i = 0; i < 4; ++i)
            #pragma unroll
            for (int j = 0; j < 4; ++j)
                acc[i][j] = __builtin_amdgcn_mfma_f32_16x16x32_bf16(afr[i], bfr[j], acc[i][j], 0, 0, 0);
        __syncthreads();
    }

    // Epilogue: D[m = quad*4+reg][n = lane&15]  (m89/m91-verified C/D mapping)
    float bcs[4];
    #pragma unroll
    for (int j = 0; j < 4; ++j) bcs[j] = bias[bn * 128 + wn + j * 16 + l15];
    #pragma unroll
    for (int i = 0; i < 4; ++i) {
        const int rowb = bm * 128 + wm + i * 16 + quad * 4;
        #pragma unroll
        for (int r = 0; r < 4; ++r) {
            #pragma unroll
            for (int j = 0; j < 4; ++j) {
                const int col  = bn * 128 + wn + j * 16 + l15;
                const float v  = acc[i][j][r] + bcs[j];
                if constexpr (HALF)
                    curh[(size_t)(rowb + r) * GOUT + col] = f2h(v);
                else
                    cur[(size_t)(rowb + r) * GOUT + col] = v;
            }
        }
    }
}

// ---------------------------------------------------------------------------
// Chunk-parallel scan (affine until first spike; exact kernel covers spikes).
// ---------------------------------------------------------------------------
static __device__ __forceinline__ void alif_mat(
    float dv, float db, float be,
    float& a00, float& a01, float& a10, float& a11, float& g0, float& g1)
{
    a00 = dv;
    a01 = -(1.0f - dv);
    g0  = (1.0f - dv);
    a10 = (1.0f - db) * be * dv;
    a11 = db - (1.0f - db) * be * (1.0f - dv);
    g1  = (1.0f - db) * be * (1.0f - dv);
}

// fp16-cur pass1: 2 neurons/thread (uint cur loads, f4v u store, 2-way ILP)
__global__ __launch_bounds__(256) void alif_pass1_h(
    const unsigned short* __restrict__ curh,
    const float* __restrict__ beta, const float* __restrict__ decay_v,
    const float* __restrict__ decay_b, float2* __restrict__ u)
{
    const int gid = blockIdx.x * 256 + threadIdx.x;   // GB*NCH*256 threads
    const int o2  = gid & 255;
    const int o   = o2 * 2;
    const int r   = gid >> 8;
    const int c   = r % NCH;
    const int b   = r / NCH;
    const float2 dv2 = ((const float2*)decay_v)[o2];
    const float2 db2 = ((const float2*)decay_b)[o2];
    const float2 be2 = ((const float2*)beta)[o2];
    float a00, a01, a10, a11, g0, g1;
    float A00, A01, A10, A11, G0, G1;
    alif_mat(dv2.x, db2.x, be2.x, a00, a01, a10, a11, g0, g1);
    alif_mat(dv2.y, db2.y, be2.y, A00, A01, A10, A11, G0, G1);

    const uint32_t* cp = (const uint32_t*)(curh + ((size_t)b * GT + (size_t)c * CHL) * GOUT + o);
    float v0 = 0.f, w0 = 0.f, v1 = 0.f, w1 = 0.f;
    uint32_t buf[10];
    #pragma unroll
    for (int j = 0; j < 10; ++j) buf[j] = cp[(size_t)j * 256];
    for (int t0 = 0; t0 < CHL; t0 += 10) {
        uint32_t nxt[10];
        const bool more = (t0 + 10 < CHL);
        if (more) {
            #pragma unroll
            for (int j = 0; j < 10; ++j) nxt[j] = cp[(size_t)(t0 + 10 + j) * 256];
        }
        #pragma unroll
        for (int j = 0; j < 10; ++j) {
            const float c0 = lo_h(buf[j]);
            const float c1 = hi_h(buf[j]);
            float nv = a00 * v0 + a01 * w0 + g0 * c0;
            float nw = a10 * v0 + a11 * w0 + g1 * c0;
            v0 = nv; w0 = nw;
            nv = A00 * v1 + A01 * w1 + G0 * c1;
            nw = A10 * v1 + A11 * w1 + G1 * c1;
            v1 = nv; w1 = nw;
        }
        if (more) {
            #pragma unroll
            for (int j = 0; j < 10; ++j) buf[j] = nxt[j];
        }
    }
    f4v s = {v0, w0, v1, w1};
    *(f4v*)(u + ((size_t)b * NCH + c) * GOUT + o) = s;
}

// legacy fp32 pass1 (fallback path, unchanged)
__global__ __launch_bounds__(256) void alif_pass1(
    const float* __restrict__ out,
    const float* __restrict__ beta, const float* __restrict__ decay_v,
    const float* __restrict__ decay_b, float2* __restrict__ u)
{
    const int gid = blockIdx.x * 256 + threadIdx.x;
    const int o = gid & (GOUT - 1);
    const int r = gid >> 9;
    const int c = r % NCH;
    const int b = r / NCH;
    float a00, a01, a10, a11, g0, g1;
    alif_mat(decay_v[o], decay_b[o], beta[o], a00, a01, a10, a11, g0, g1);

    const float* cp = out + ((size_t)b * GT + c * CHL) * GOUT + o;
    float v = 0.f, w = 0.f;
    float buf[10];
    #pragma unroll
    for (int j = 0; j < 10; ++j) buf[j] = cp[(size_t)j * GOUT];
    for (int t0 = 0; t0 < CHL; t0 += 10) {
        float nxt[10];
        const bool more = (t0 + 10 < CHL);
        if (more) {
            #pragma unroll
            for (int j = 0; j < 10; ++j) nxt[j] = cp[(size_t)(t0 + 10 + j) * GOUT];
        }
        #pragma unroll
        for (int j = 0; j < 10; ++j) {
            const float cu = buf[j];
            const float nv = a00 * v + a01 * w + g0 * cu;
            const float nw = a10 * v + a11 * w + g1 * cu;
            v = nv; w = nw;
        }
        if (more) {
            #pragma unroll
            for (int j = 0; j < 10; ++j) buf[j] = nxt[j];
        }
    }
    u[((size_t)b * NCH + c) * GOUT + o] = make_float2(v, w);
}

__global__ __launch_bounds__(256) void alif_pass2(
    float2* __restrict__ u,
    const float* __restrict__ beta, const float* __restrict__ decay_v,
    const float* __restrict__ decay_b)
{
    const int gid = blockIdx.x * 256 + threadIdx.x;   // 32768 threads
    const int o = gid & (GOUT - 1);
    const int b = gid >> 9;
    float a00, a01, a10, a11, g0, g1;
    alif_mat(decay_v[o], decay_b[o], beta[o], a00, a01, a10, a11, g0, g1);
    float p00 = 1.f, p01 = 0.f, p10 = 0.f, p11 = 1.f;
    for (int i = 0; i < CHL; ++i) {
        const float n00 = a00 * p00 + a01 * p10, n01 = a00 * p01 + a01 * p11;
        const float n10 = a10 * p00 + a11 * p10, n11 = a10 * p01 + a11 * p11;
        p00 = n00; p01 = n01; p10 = n10; p11 = n11;
    }
    float Sv = 0.f, Sb = 0.f;
    for (int c = 0; c < NCH; ++c) {
        const size_t idx = ((size_t)b * NCH + c) * GOUT + o;
        const float2 t = u[idx];
        u[idx] = make_float2(Sv, Sb);                  // seed for chunk c
        const float nSv = p00 * Sv + p01 * Sb + t.x;
        const float nSb = p10 * Sv + p11 * Sb + t.y;
        Sv = nSv; Sb = nSb;
    }
}

// fp16-cur pass3: 2 neurons/thread, NT float2 stores on all 4 output streams.
// cur lives in ws -> zs writes are pure streaming (no in-place aliasing).
__global__ __launch_bounds__(256) void alif_pass3_h(
    const unsigned short* __restrict__ curh, float* __restrict__ out,
    const float2* __restrict__ seed,
    const float* __restrict__ beta, const float* __restrict__ beta2,
    const float* __restrict__ decay_v, const float* __restrict__ decay_b,
    unsigned int* __restrict__ flag)
{
    const int gid = blockIdx.x * 256 + threadIdx.x;   // GB*NCH*256 threads
    const int o2  = gid & 255;
    const int o   = o2 * 2;
    const int r   = gid >> 8;
    const int c   = r % NCH;
    const int b   = r / NCH;
    const float2 dv2 = ((const float2*)decay_v)[o2];
    const float2 db2 = ((const float2*)decay_b)[o2];
    const float2 be_ = ((const float2*)beta)[o2];
    const float2 b2_ = ((const float2*)beta2)[o2];

    const int tbase = c * CHL;
    const uint32_t* cp = (const uint32_t*)(curh + ((size_t)b * GT + tbase) * GOUT + o);
    float* zsp = out + ((size_t)b * GT + tbase) * GOUT + o;
    const size_t SB = (size_t)GB * GT * GOUT;
    const size_t PL = (size_t)GB * (GT + 1) * GOUT;
    float* vf  = out + SB + ((size_t)b * (GT + 1) + tbase + 1) * GOUT + o;
    float* zf  = vf + PL;
    float* bfp = vf + 2 * PL;
    if (c == 0) {   // t=0 pads
        nts2(vf  - GOUT, 0.f, 0.f);
        nts2(zf  - GOUT, 0.f, 0.f);
        nts2(bfp - GOUT, 0.f, 0.f);
    }

    const f4v s0 = *(const f4v*)(seed + ((size_t)b * NCH + c) * GOUT + o);
    float v0 = s0.x, ba0 = s0.y, v1 = s0.z, ba1 = s0.w;
    float z0 = 0.f, z1 = 0.f;
    bool any = false;
    uint32_t buf[10];
    #pragma unroll
    for (int j = 0; j < 10; ++j) buf[j] = cp[(size_t)j * 256];

    for (int t0 = 0; t0 < CHL; t0 += 10) {
        uint32_t nxt[10];
        const bool more = (t0 + 10 < CHL);
        if (more) {
            #pragma unroll
            for (int j = 0; j < 10; ++j) nxt[j] = cp[(size_t)(t0 + 10 + j) * 256];
        }
        #pragma unroll
        for (int j = 0; j < 10; ++j) {
            const int t = t0 + j;
            const float c0 = lo_h(buf[j]);
            const float c1 = hi_h(buf[j]);
            v0 *= (1.0f - z0);
            v0 = dv2.x * v0 + (1.0f - dv2.x) * (c0 - ba0);
            z0 = (v0 >= 1.0f) ? 1.0f : 0.0f;          // THR = 1.0
            ba0 = db2.x * ba0 + (1.0f - db2.x) * (be_.x * v0 + b2_.x * z0);
            v1 *= (1.0f - z1);
            v1 = dv2.y * v1 + (1.0f - dv2.y) * (c1 - ba1);
            z1 = (v1 >= 1.0f) ? 1.0f : 0.0f;
            ba1 = db2.y * ba1 + (1.0f - db2.y) * (be_.y * v1 + b2_.y * z1);
            any = any || (z0 != 0.0f) || (z1 != 0.0f);
            nts2(zsp + (size_t)t * GOUT, z0, z1);
            nts2(vf  + (size_t)t * GOUT, v0, v1);
            nts2(zf  + (size_t)t * GOUT, z0, z1);
            nts2(bfp + (size_t)t * GOUT, ba0, ba1);
        }
        if (more) {
            #pragma unroll
            for (int j = 0; j < 10; ++j) buf[j] = nxt[j];
        }
    }
    if (any) atomicOr(flag, 1u);
}

// legacy fp32 pass3 (fallback path, unchanged: in-place cur->zs)
__global__ __launch_bounds__(256) void alif_pass3(
    float* __restrict__ out, const float2* __restrict__ seed,
    const float* __restrict__ beta, const float* __restrict__ beta2,
    const float* __restrict__ decay_v, const float* __restrict__ decay_b,
    unsigned int* __restrict__ flag)
{
    const int gid = blockIdx.x * 256 + threadIdx.x;
    const int o = gid & (GOUT - 1);
    const int r = gid >> 9;
    const int c = r % NCH;
    const int b = r / NCH;
    const float dv = decay_v[o], db = decay_b[o];
    const float be = beta[o],    be2 = beta2[o];

    const int tbase = c * CHL;
    float* curp = out + ((size_t)b * GT + tbase) * GOUT + o;
    const size_t SB = (size_t)GB * GT * GOUT;
    const size_t PL = (size_t)GB * (GT + 1) * GOUT;
    float* vf  = out + SB + ((size_t)b * (GT + 1) + tbase + 1) * GOUT + o;
    float* zf  = vf + PL;
    float* bfp = vf + 2 * PL;
    if (c == 0) {
        vf[-(ptrdiff_t)GOUT] = 0.f; zf[-(ptrdiff_t)GOUT] = 0.f; bfp[-(ptrdiff_t)GOUT] = 0.f;
    }

    const float2 s0 = seed[((size_t)b * NCH + c) * GOUT + o];
    float v = s0.x, ba = s0.y, z = 0.f;
    bool any = false;
    float buf[10];
    #pragma unroll
    for (int j = 0; j < 10; ++j) buf[j] = curp[(size_t)j * GOUT];

    for (int t0 = 0; t0 < CHL; t0 += 10) {
        float nxt[10];
        const bool more = (t0 + 10 < CHL);
        if (more) {
            #pragma unroll
            for (int j = 0; j < 10; ++j) nxt[j] = curp[(size_t)(t0 + 10 + j) * GOUT];
        }
        #pragma unroll
        for (int j = 0; j < 10; ++j) {
            const int t = t0 + j;
            v *= (1.0f - z);
            v = dv * v + (1.0f - dv) * (buf[j] - ba);
            z = (v >= 1.0f) ? 1.0f : 0.0f;
            ba = db * ba + (1.0f - db) * (be * v + be2 * z);
            any = any || (z != 0.0f);
            curp[(size_t)t * GOUT]     = z;
            vf[(size_t)t * GOUT]       = v;
            zf[(size_t)t * GOUT]       = z;
            bfp[(size_t)t * GOUT]      = ba;
        }
        if (more) {
            #pragma unroll
            for (int j = 0; j < 10; ++j) buf[j] = nxt[j];
        }
    }
    if (any) atomicOr(flag, 1u);
}

// Monolithic fallback scan (used only if ws_size is too small for seeds)
__global__ __launch_bounds__(128) void alif_scan(
    float* __restrict__ out,
    const float* __restrict__ beta, const float* __restrict__ beta2,
    const float* __restrict__ decay_v, const float* __restrict__ decay_b,
    unsigned int* __restrict__ flag)
{
    const int gid = blockIdx.x * 128 + threadIdx.x;
    const int o = gid & (GOUT - 1);
    const int b = gid >> 9;
    const float dv = decay_v[o], db = decay_b[o];
    const float be = beta[o],    be2 = beta2[o];
    float* curp = out + (size_t)b * GT * GOUT + o;
    const size_t SB = (size_t)GB * GT * GOUT;
    const size_t PL = (size_t)GB * (GT + 1) * GOUT;
    float* vf  = out + SB + (size_t)b * (GT + 1) * GOUT + o;
    float* zf  = vf + PL;
    float* bfp = vf + 2 * PL;
    vf[0] = 0.f; zf[0] = 0.f; bfp[0] = 0.f;
    float v = 0.f, z = 0.f, ba = 0.f;
    bool any = false;
    float buf[8];
    #pragma unroll
    for (int j = 0; j < 8; ++j) buf[j] = curp[(size_t)j * GOUT];
    for (int t0 = 0; t0 < GT; t0 += 8) {
        float nxt[8];
        const bool more = (t0 + 8 < GT);
        if (more) {
            #pragma unroll
            for (int j = 0; j < 8; ++j) nxt[j] = curp[(size_t)(t0 + 8 + j) * GOUT];
        }
        #pragma unroll
        for (int j = 0; j < 8; ++j) {
            const int t = t0 + j;
            v *= (1.0f - z);
            v = dv * v + (1.0f - dv) * (buf[j] - ba);
            z = (v >= 1.0f) ? 1.0f : 0.0f;
            ba = db * ba + (1.0f - db) * (be * v + be2 * z);
            any = any || (z != 0.0f);
            curp[(size_t)t * GOUT]      = z;
            vf[(size_t)(t + 1) * GOUT]  = v;
            zf[(size_t)(t + 1) * GOUT]  = z;
            bfp[(size_t)(t + 1) * GOUT] = ba;
        }
        if (more) {
            #pragma unroll
            for (int j = 0; j < 8; ++j) buf[j] = nxt[j];
        }
    }
    if (any) atomicOr(flag, 1u);
}

// Exact fallback with full recurrent coupling (early-exits on flag==0, ~2us)
__global__ __launch_bounds__(512) void alif_exact(
    const float* __restrict__ X, const float* __restrict__ W,
    const float* __restrict__ bias, const float* __restrict__ R,
    const float* __restrict__ beta, const float* __restrict__ beta2,
    const float* __restrict__ decay_v, const float* __restrict__ decay_b,
    float* __restrict__ out, const unsigned int* __restrict__ flag)
{
    if (*flag == 0u) return;
    const int b = blockIdx.x;
    const int o = threadIdx.x;
    __shared__ float xs[GIN];
    __shared__ float zsh[GOUT];
    __shared__ int sflag;
    const float dv = decay_v[o], db = decay_b[o];
    const float be = beta[o],    be2 = beta2[o];
    const float bi = bias[o];
    float* zsp = out + (size_t)b * GT * GOUT + o;
    const size_t SB = (size_t)GB * GT * GOUT, PL = (size_t)GB * (GT + 1) * GOUT;
    float* vf  = out + SB + (size_t)b * (GT + 1) * GOUT + o;
    float* zf  = vf + PL;
    float* bfp = vf + 2 * PL;
    vf[0] = 0.f; zf[0] = 0.f; bfp[0] = 0.f;
    float v = 0.f, z = 0.f, ba = 0.f;
    const float* wr = W + (size_t)o * GIN;
    const float* rr = R + (size_t)o * GOUT;
    for (int t = 0; t < GT; ++t) {
        __syncthreads();
        xs[o]  = X[((size_t)b * GT + t) * GIN + o];
        zsh[o] = z;
        if (o == 0) sflag = 0;
        __syncthreads();
        if (z != 0.f) sflag = 1;
        __syncthreads();
        float cur = bi;
        #pragma unroll 8
        for (int i = 0; i < GIN; ++i) cur += wr[i] * xs[i];
        if (sflag) {
            #pragma unroll 8
            for (int i = 0; i < GOUT; ++i) cur += rr[i] * zsh[i];
        }
        v *= (1.f - z);
        v = dv * v + (1.f - dv) * (cur - ba);
        z = (v >= 1.f) ? 1.f : 0.f;
        ba = db * ba + (1.f - db) * (be * v + be2 * z);
        zsp[(size_t)t * GOUT]       = z;
        vf[(size_t)(t + 1) * GOUT]  = v;
        zf[(size_t)(t + 1) * GOUT]  = z;
        bfp[(size_t)(t + 1) * GOUT] = ba;
    }
}

extern "C" void kernel_launch(void* const* d_in, const int* in_sizes, int n_in,
                              void* d_out, int out_size, void* d_ws, size_t ws_size,
                              hipStream_t stream)
{
    const float* X     = (const float*)d_in[0];
    const float* W     = (const float*)d_in[1];
    const float* bias  = (const float*)d_in[2];
    const float* R     = (const float*)d_in[3];
    const float* beta  = (const float*)d_in[4];
    const float* beta2 = (const float*)d_in[5];
    const float* dv    = (const float*)d_in[6];
    const float* db    = (const float*)d_in[7];
    float* out = (float*)d_out;
    unsigned int* flag = (unsigned int*)d_ws;

    // bf16 staging buffers live in the states region of d_out (overwritten
    // only by pass3/scan, which run strictly after the GEMM on this stream).
    const size_t SB = (size_t)GB * GT * GOUT;
    unsigned short* Xh = (unsigned short*)(out + SB);
    unsigned short* Wh = Xh + (size_t)GM * GIN;

    const size_t seeds_b = (size_t)GB * NCH * GOUT * sizeof(float2);  // 5.24 MB
    const size_t need_f  = 256 + seeds_b;
    const size_t need_h  = need_f + (size_t)GM * GOUT * 2;            // +65.5 MB fp16 cur

    alif_cvt<<<dim3((NX8 + NW8) / 256), dim3(256), 0, stream>>>(X, W, Xh, Wh, flag);

    if (ws_size >= need_h) {
        // primary path: fp16 cur in workspace (L3-resident between passes)
        float2* u = (float2*)((char*)d_ws + 256);
        unsigned short* curh = (unsigned short*)((char*)d_ws + need_f);
        alif_gemm<true><<<dim3(500 * 4), dim3(256), 0, stream>>>(Xh, Wh, bias, nullptr, curh);
        alif_pass1_h<<<dim3(GB * NCH * GOUT / 512), dim3(256), 0, stream>>>(curh, beta, dv, db, u);
        alif_pass2<<<dim3(GB * GOUT / 256), dim3(256), 0, stream>>>(u, beta, dv, db);
        alif_pass3_h<<<dim3(GB * NCH * GOUT / 512), dim3(256), 0, stream>>>(curh, out, u, beta, beta2, dv, db, flag);
    } else if (ws_size >= need_f) {
        // legacy path: fp32 cur in the zs region of d_out
        float2* u = (float2*)((char*)d_ws + 256);
        alif_gemm<false><<<dim3(500 * 4), dim3(256), 0, stream>>>(Xh, Wh, bias, out, nullptr);
        alif_pass1<<<dim3(GB * NCH * GOUT / 256), dim3(256), 0, stream>>>(out, beta, dv, db, u);
        alif_pass2<<<dim3(GB * GOUT / 256), dim3(256), 0, stream>>>(u, beta, dv, db);
        alif_pass3<<<dim3(GB * NCH * GOUT / 256), dim3(256), 0, stream>>>(out, u, beta, beta2, dv, db, flag);
    } else {
        alif_gemm<false><<<dim3(500 * 4), dim3(256), 0, stream>>>(Xh, Wh, bias, out, nullptr);
        alif_scan<<<dim3(256), dim3(128), 0, stream>>>(out, beta, beta2, dv, db, flag);
    }
    alif_exact<<<dim3(GB), dim3(512), 0, stream>>>(X, W, bias, R, beta, beta2, dv, db, out, flag);
}

// Round 3
// 679.710 us; speedup vs baseline: 1.0852x; 1.0128x over previous
//
#include <hip/hip_runtime.h>
#include <stdint.h>

// Problem constants (from reference)
#define GB   64      // batch
#define GT   1000    // timesteps
#define GIN  512
#define GOUT 512
#define GM   (GB*GT) // 64000 GEMM rows
#define NCH  20      // scan chunks
#define CHL  50      // chunk length (NCH*CHL == GT)

typedef __attribute__((ext_vector_type(8))) __bf16 bf8_t;   // MFMA A/B frag
typedef __attribute__((ext_vector_type(4))) float f4_t;     // MFMA C/D frag
typedef __attribute__((ext_vector_type(8))) unsigned short us8_t;
typedef __attribute__((ext_vector_type(2))) float f2v;
typedef __attribute__((ext_vector_type(4))) float f4v;

typedef __attribute__((address_space(1))) const uint32_t gu32_t;
typedef __attribute__((address_space(3))) uint32_t lu32_t;

static __device__ __forceinline__ unsigned short f2bf(float f) {
    // round-to-nearest-even fp32 -> bf16 bits
    union { float f; unsigned u; } v; v.f = f;
    unsigned r = v.u + 0x7fffu + ((v.u >> 16) & 1u);
    return (unsigned short)(r >> 16);
}

static __device__ __forceinline__ unsigned short f2h(float f) {
    _Float16 h = (_Float16)f;          // v_cvt_f16_f32 (RTN)
    unsigned short s; __builtin_memcpy(&s, &h, 2);
    return s;
}
static __device__ __forceinline__ float lo_h(uint32_t u) {
    unsigned short s = (unsigned short)(u & 0xffffu);
    _Float16 h; __builtin_memcpy(&h, &s, 2);
    return (float)h;
}
static __device__ __forceinline__ float hi_h(uint32_t u) {
    unsigned short s = (unsigned short)(u >> 16);
    _Float16 h; __builtin_memcpy(&h, &s, 2);
    return (float)h;
}
// nontemporal float2 store (write-once output streams: don't pollute L2/L3)
static __device__ __forceinline__ void nts2(float* p, float x, float y) {
    f2v v = {x, y};
    __builtin_nontemporal_store(v, (f2v*)p);
}

// ---------------------------------------------------------------------------
// Tiny one-time fp32 -> bf16 conversion of W (0.262M elems, 524 KB out).
// Destination lives in the states region of d_out (overwritten only by pass3,
// which runs after the GEMM -- stream order makes this safe).
// Also clears the spike flag.
// ---------------------------------------------------------------------------
#define NW8 32768     // 262144/8
__global__ __launch_bounds__(256) void alif_cvt_w(
    const float* __restrict__ W, unsigned short* __restrict__ Wh,
    unsigned int* __restrict__ flag)
{
    if (blockIdx.x == 0 && threadIdx.x == 0) *flag = 0u;
    const size_t i = (size_t)blockIdx.x * 256 + threadIdx.x;   // < NW8
    const float* src = W + i * 8;
    unsigned short* dst = Wh + i * 8;
    const f4v a = *(const f4v*)src;
    const f4v b = *((const f4v*)src + 1);
    us8_t r;
    r[0] = f2bf(a.x); r[1] = f2bf(a.y); r[2] = f2bf(a.z); r[3] = f2bf(a.w);
    r[4] = f2bf(b.x); r[5] = f2bf(b.y); r[6] = f2bf(b.z); r[7] = f2bf(b.w);
    *(us8_t*)dst = r;
}

// ---------------------------------------------------------------------------
// Fused-conversion GEMM: cur[m][n] = X[m][k] . W[n][k] + bias[n]
// Tile 128(M) x 512(N=full) x 32(K), 512 threads (8 waves, 2m x 4n).
//  - A: X fp32 read ONCE per panel (NT), reg-staged -> f2bf -> ds_write_b128.
//  - B: W bf16 (L2-resident, 524 KB) via global_load_lds width-16.
//  - 2-phase LDS double-buffer: stage(k+1) issued before MFMA(k), single
//    barrier per K-step (T3-minimum recipe) -- needed since ~175 VGPR
//    leaves 1 block/CU (no inter-block overlap to hide staging).
// HALF=true: fp16 cur into workspace. HALF=false: fp32 cur into d_out.
// ---------------------------------------------------------------------------
template<bool HALF>
__global__ __launch_bounds__(512) void alif_gemmf(
    const float* __restrict__ X, const unsigned short* __restrict__ Wh,
    const float* __restrict__ bias, float* __restrict__ cur,
    unsigned short* __restrict__ curh)
{
    __shared__ unsigned short As[2][128 * 32];   // 2 x 8 KB
    __shared__ unsigned short Bs[2][512 * 32];   // 2 x 32 KB
    const int tid  = threadIdx.x;
    const int bm   = blockIdx.x;          // 0..499
    const int lane = tid & 63;
    const int wave = tid >> 6;            // 0..7
    const int wm   = (wave >> 2) * 64;    // 0,64
    const int wn   = (wave & 3) * 128;    // 0,128,256,384
    const int quad = lane >> 4;
    const int l15  = lane & 15;
    // A staging: 512 threads cover 128 rows x 32 k of fp32 X (8 elems/thread)
    const int arow = tid >> 2;            // 0..127
    const int acol = (tid & 3) * 8;       // 0,8,16,24
    // B staging: per-wave gll segments (1 KB = 16 n-rows each)
    const int brow4 = lane >> 2;          // 0..15
    const int bcol  = (lane & 3) * 8;

    const size_t m0 = (size_t)bm * 128;
    const float* ap = X + (m0 + arow) * GIN + acol;

    f4_t acc[4][8];
    #pragma unroll
    for (int i = 0; i < 4; ++i)
        #pragma unroll
        for (int j = 0; j < 8; ++j) acc[i][j] = (f4_t)(0.0f);

    // ---- prologue: stage k-step 0 into buffer 0 ----
    f4v pa0 = __builtin_nontemporal_load((const f4v*)ap);
    f4v pa1 = __builtin_nontemporal_load((const f4v*)ap + 1);
    #pragma unroll
    for (int s = wave; s < 32; s += 8) {
        const unsigned short* gb = Wh + (size_t)(s * 16 + brow4) * GIN + bcol;
        __builtin_amdgcn_global_load_lds((gu32_t*)gb, (lu32_t*)&Bs[0][s * 512], 16, 0, 0);
    }
    {
        us8_t r;
        r[0] = f2bf(pa0.x); r[1] = f2bf(pa0.y); r[2] = f2bf(pa0.z); r[3] = f2bf(pa0.w);
        r[4] = f2bf(pa1.x); r[5] = f2bf(pa1.y); r[6] = f2bf(pa1.z); r[7] = f2bf(pa1.w);
        *(us8_t*)&As[0][arow * 32 + acol] = r;
    }
    __syncthreads();

    // ---- main loop: 16 K-steps, 2-phase pipeline ----
    for (int kk = 0; kk < 16; ++kk) {
        const int cb = kk & 1;
        const bool pre = (kk + 1 < 16);
        if (pre) {
            const float* apn = ap + (kk + 1) * 32;
            pa0 = __builtin_nontemporal_load((const f4v*)apn);
            pa1 = __builtin_nontemporal_load((const f4v*)apn + 1);
            const int k1 = (kk + 1) * 32;
            #pragma unroll
            for (int s = wave; s < 32; s += 8) {
                const unsigned short* gb = Wh + (size_t)(s * 16 + brow4) * GIN + k1 + bcol;
                __builtin_amdgcn_global_load_lds((gu32_t*)gb, (lu32_t*)&Bs[cb ^ 1][s * 512], 16, 0, 0);
            }
        }
        bf8_t afr[4];
        #pragma unroll
        for (int i = 0; i < 4; ++i)
            afr[i] = *(const bf8_t*)&As[cb][(wm + i * 16 + l15) * 32 + quad * 8];
        #pragma unroll
        for (int j = 0; j < 8; ++j) {
            const bf8_t bfr = *(const bf8_t*)&Bs[cb][(wn + j * 16 + l15) * 32 + quad * 8];
            #pragma unroll
            for (int i = 0; i < 4; ++i)
                acc[i][j] = __builtin_amdgcn_mfma_f32_16x16x32_bf16(afr[i], bfr, acc[i][j], 0, 0, 0);
        }
        if (pre) {
            us8_t r;
            r[0] = f2bf(pa0.x); r[1] = f2bf(pa0.y); r[2] = f2bf(pa0.z); r[3] = f2bf(pa0.w);
            r[4] = f2bf(pa1.x); r[5] = f2bf(pa1.y); r[6] = f2bf(pa1.z); r[7] = f2bf(pa1.w);
            *(us8_t*)&As[cb ^ 1][arow * 32 + acol] = r;
        }
        __syncthreads();
    }

    // Epilogue: D[m = quad*4+reg][n = lane&15]  (m89/m91-verified C/D mapping)
    float bcs[8];
    #pragma unroll
    for (int j = 0; j < 8; ++j) bcs[j] = bias[wn + j * 16 + l15];
    #pragma unroll
    for (int i = 0; i < 4; ++i) {
        const size_t rowb = m0 + wm + i * 16 + quad * 4;
        #pragma unroll
        for (int r = 0; r < 4; ++r) {
            #pragma unroll
            for (int j = 0; j < 8; ++j) {
                const int col = wn + j * 16 + l15;
                const float v = acc[i][j][r] + bcs[j];
                if constexpr (HALF)
                    curh[(rowb + r) * GOUT + col] = f2h(v);
                else
                    cur[(rowb + r) * GOUT + col] = v;
            }
        }
    }
}

// ---------------------------------------------------------------------------
// Chunk-parallel scan (affine until first spike; exact kernel covers spikes).
// ---------------------------------------------------------------------------
static __device__ __forceinline__ void alif_mat(
    float dv, float db, float be,
    float& a00, float& a01, float& a10, float& a11, float& g0, float& g1)
{
    a00 = dv;
    a01 = -(1.0f - dv);
    g0  = (1.0f - dv);
    a10 = (1.0f - db) * be * dv;
    a11 = db - (1.0f - db) * be * (1.0f - dv);
    g1  = (1.0f - db) * be * (1.0f - dv);
}

// fp16-cur pass1: 2 neurons/thread (uint cur loads, f4v u store, 2-way ILP)
__global__ __launch_bounds__(256) void alif_pass1_h(
    const unsigned short* __restrict__ curh,
    const float* __restrict__ beta, const float* __restrict__ decay_v,
    const float* __restrict__ decay_b, float2* __restrict__ u)
{
    const int gid = blockIdx.x * 256 + threadIdx.x;   // GB*NCH*256 threads
    const int o2  = gid & 255;
    const int o   = o2 * 2;
    const int r   = gid >> 8;
    const int c   = r % NCH;
    const int b   = r / NCH;
    const float2 dv2 = ((const float2*)decay_v)[o2];
    const float2 db2 = ((const float2*)decay_b)[o2];
    const float2 be2 = ((const float2*)beta)[o2];
    float a00, a01, a10, a11, g0, g1;
    float A00, A01, A10, A11, G0, G1;
    alif_mat(dv2.x, db2.x, be2.x, a00, a01, a10, a11, g0, g1);
    alif_mat(dv2.y, db2.y, be2.y, A00, A01, A10, A11, G0, G1);

    const uint32_t* cp = (const uint32_t*)(curh + ((size_t)b * GT + (size_t)c * CHL) * GOUT + o);
    float v0 = 0.f, w0 = 0.f, v1 = 0.f, w1 = 0.f;
    uint32_t buf[10];
    #pragma unroll
    for (int j = 0; j < 10; ++j) buf[j] = cp[(size_t)j * 256];
    for (int t0 = 0; t0 < CHL; t0 += 10) {
        uint32_t nxt[10];
        const bool more = (t0 + 10 < CHL);
        if (more) {
            #pragma unroll
            for (int j = 0; j < 10; ++j) nxt[j] = cp[(size_t)(t0 + 10 + j) * 256];
        }
        #pragma unroll
        for (int j = 0; j < 10; ++j) {
            const float c0 = lo_h(buf[j]);
            const float c1 = hi_h(buf[j]);
            float nv = a00 * v0 + a01 * w0 + g0 * c0;
            float nw = a10 * v0 + a11 * w0 + g1 * c0;
            v0 = nv; w0 = nw;
            nv = A00 * v1 + A01 * w1 + G0 * c1;
            nw = A10 * v1 + A11 * w1 + G1 * c1;
            v1 = nv; w1 = nw;
        }
        if (more) {
            #pragma unroll
            for (int j = 0; j < 10; ++j) buf[j] = nxt[j];
        }
    }
    f4v s = {v0, w0, v1, w1};
    *(f4v*)(u + ((size_t)b * NCH + c) * GOUT + o) = s;
}

// legacy fp32 pass1 (fallback path, unchanged)
__global__ __launch_bounds__(256) void alif_pass1(
    const float* __restrict__ out,
    const float* __restrict__ beta, const float* __restrict__ decay_v,
    const float* __restrict__ decay_b, float2* __restrict__ u)
{
    const int gid = blockIdx.x * 256 + threadIdx.x;
    const int o = gid & (GOUT - 1);
    const int r = gid >> 9;
    const int c = r % NCH;
    const int b = r / NCH;
    float a00, a01, a10, a11, g0, g1;
    alif_mat(decay_v[o], decay_b[o], beta[o], a00, a01, a10, a11, g0, g1);

    const float* cp = out + ((size_t)b * GT + c * CHL) * GOUT + o;
    float v = 0.f, w = 0.f;
    float buf[10];
    #pragma unroll
    for (int j = 0; j < 10; ++j) buf[j] = cp[(size_t)j * GOUT];
    for (int t0 = 0; t0 < CHL; t0 += 10) {
        float nxt[10];
        const bool more = (t0 + 10 < CHL);
        if (more) {
            #pragma unroll
            for (int j = 0; j < 10; ++j) nxt[j] = cp[(size_t)(t0 + 10 + j) * GOUT];
        }
        #pragma unroll
        for (int j = 0; j < 10; ++j) {
            const float cu = buf[j];
            const float nv = a00 * v + a01 * w + g0 * cu;
            const float nw = a10 * v + a11 * w + g1 * cu;
            v = nv; w = nw;
        }
        if (more) {
            #pragma unroll
            for (int j = 0; j < 10; ++j) buf[j] = nxt[j];
        }
    }
    u[((size_t)b * NCH + c) * GOUT + o] = make_float2(v, w);
}

__global__ __launch_bounds__(256) void alif_pass2(
    float2* __restrict__ u,
    const float* __restrict__ beta, const float* __restrict__ decay_v,
    const float* __restrict__ decay_b)
{
    const int gid = blockIdx.x * 256 + threadIdx.x;   // 32768 threads
    const int o = gid & (GOUT - 1);
    const int b = gid >> 9;
    float a00, a01, a10, a11, g0, g1;
    alif_mat(decay_v[o], decay_b[o], beta[o], a00, a01, a10, a11, g0, g1);
    float p00 = 1.f, p01 = 0.f, p10 = 0.f, p11 = 1.f;
    for (int i = 0; i < CHL; ++i) {
        const float n00 = a00 * p00 + a01 * p10, n01 = a00 * p01 + a01 * p11;
        const float n10 = a10 * p00 + a11 * p10, n11 = a10 * p01 + a11 * p11;
        p00 = n00; p01 = n01; p10 = n10; p11 = n11;
    }
    float Sv = 0.f, Sb = 0.f;
    for (int c = 0; c < NCH; ++c) {
        const size_t idx = ((size_t)b * NCH + c) * GOUT + o;
        const float2 t = u[idx];
        u[idx] = make_float2(Sv, Sb);                  // seed for chunk c
        const float nSv = p00 * Sv + p01 * Sb + t.x;
        const float nSb = p10 * Sv + p11 * Sb + t.y;
        Sv = nSv; Sb = nSb;
    }
}

// fp16-cur pass3: 2 neurons/thread, NT float2 stores on all 4 output streams.
// cur lives in ws -> zs writes are pure streaming (no in-place aliasing).
__global__ __launch_bounds__(256) void alif_pass3_h(
    const unsigned short* __restrict__ curh, float* __restrict__ out,
    const float2* __restrict__ seed,
    const float* __restrict__ beta, const float* __restrict__ beta2,
    const float* __restrict__ decay_v, const float* __restrict__ decay_b,
    unsigned int* __restrict__ flag)
{
    const int gid = blockIdx.x * 256 + threadIdx.x;   // GB*NCH*256 threads
    const int o2  = gid & 255;
    const int o   = o2 * 2;
    const int r   = gid >> 8;
    const int c   = r % NCH;
    const int b   = r / NCH;
    const float2 dv2 = ((const float2*)decay_v)[o2];
    const float2 db2 = ((const float2*)decay_b)[o2];
    const float2 be_ = ((const float2*)beta)[o2];
    const float2 b2_ = ((const float2*)beta2)[o2];

    const int tbase = c * CHL;
    const uint32_t* cp = (const uint32_t*)(curh + ((size_t)b * GT + tbase) * GOUT + o);
    float* zsp = out + ((size_t)b * GT + tbase) * GOUT + o;
    const size_t SB = (size_t)GB * GT * GOUT;
    const size_t PL = (size_t)GB * (GT + 1) * GOUT;
    float* vf  = out + SB + ((size_t)b * (GT + 1) + tbase + 1) * GOUT + o;
    float* zf  = vf + PL;
    float* bfp = vf + 2 * PL;
    if (c == 0) {   // t=0 pads
        nts2(vf  - GOUT, 0.f, 0.f);
        nts2(zf  - GOUT, 0.f, 0.f);
        nts2(bfp - GOUT, 0.f, 0.f);
    }

    const f4v s0 = *(const f4v*)(seed + ((size_t)b * NCH + c) * GOUT + o);
    float v0 = s0.x, ba0 = s0.y, v1 = s0.z, ba1 = s0.w;
    float z0 = 0.f, z1 = 0.f;
    bool any = false;
    uint32_t buf[10];
    #pragma unroll
    for (int j = 0; j < 10; ++j) buf[j] = cp[(size_t)j * 256];

    for (int t0 = 0; t0 < CHL; t0 += 10) {
        uint32_t nxt[10];
        const bool more = (t0 + 10 < CHL);
        if (more) {
            #pragma unroll
            for (int j = 0; j < 10; ++j) nxt[j] = cp[(size_t)(t0 + 10 + j) * 256];
        }
        #pragma unroll
        for (int j = 0; j < 10; ++j) {
            const int t = t0 + j;
            const float c0 = lo_h(buf[j]);
            const float c1 = hi_h(buf[j]);
            v0 *= (1.0f - z0);
            v0 = dv2.x * v0 + (1.0f - dv2.x) * (c0 - ba0);
            z0 = (v0 >= 1.0f) ? 1.0f : 0.0f;          // THR = 1.0
            ba0 = db2.x * ba0 + (1.0f - db2.x) * (be_.x * v0 + b2_.x * z0);
            v1 *= (1.0f - z1);
            v1 = dv2.y * v1 + (1.0f - dv2.y) * (c1 - ba1);
            z1 = (v1 >= 1.0f) ? 1.0f : 0.0f;
            ba1 = db2.y * ba1 + (1.0f - db2.y) * (be_.y * v1 + b2_.y * z1);
            any = any || (z0 != 0.0f) || (z1 != 0.0f);
            nts2(zsp + (size_t)t * GOUT, z0, z1);
            nts2(vf  + (size_t)t * GOUT, v0, v1);
            nts2(zf  + (size_t)t * GOUT, z0, z1);
            nts2(bfp + (size_t)t * GOUT, ba0, ba1);
        }
        if (more) {
            #pragma unroll
            for (int j = 0; j < 10; ++j) buf[j] = nxt[j];
        }
    }
    if (any) atomicOr(flag, 1u);
}

// legacy fp32 pass3 (fallback path, unchanged: in-place cur->zs)
__global__ __launch_bounds__(256) void alif_pass3(
    float* __restrict__ out, const float2* __restrict__ seed,
    const float* __restrict__ beta, const float* __restrict__ beta2,
    const float* __restrict__ decay_v, const float* __restrict__ decay_b,
    unsigned int* __restrict__ flag)
{
    const int gid = blockIdx.x * 256 + threadIdx.x;
    const int o = gid & (GOUT - 1);
    const int r = gid >> 9;
    const int c = r % NCH;
    const int b = r / NCH;
    const float dv = decay_v[o], db = decay_b[o];
    const float be = beta[o],    be2 = beta2[o];

    const int tbase = c * CHL;
    float* curp = out + ((size_t)b * GT + tbase) * GOUT + o;
    const size_t SB = (size_t)GB * GT * GOUT;
    const size_t PL = (size_t)GB * (GT + 1) * GOUT;
    float* vf  = out + SB + ((size_t)b * (GT + 1) + tbase + 1) * GOUT + o;
    float* zf  = vf + PL;
    float* bfp = vf + 2 * PL;
    if (c == 0) {
        vf[-(ptrdiff_t)GOUT] = 0.f; zf[-(ptrdiff_t)GOUT] = 0.f; bfp[-(ptrdiff_t)GOUT] = 0.f;
    }

    const float2 s0 = seed[((size_t)b * NCH + c) * GOUT + o];
    float v = s0.x, ba = s0.y, z = 0.f;
    bool any = false;
    float buf[10];
    #pragma unroll
    for (int j = 0; j < 10; ++j) buf[j] = curp[(size_t)j * GOUT];

    for (int t0 = 0; t0 < CHL; t0 += 10) {
        float nxt[10];
        const bool more = (t0 + 10 < CHL);
        if (more) {
            #pragma unroll
            for (int j = 0; j < 10; ++j) nxt[j] = curp[(size_t)(t0 + 10 + j) * GOUT];
        }
        #pragma unroll
        for (int j = 0; j < 10; ++j) {
            const int t = t0 + j;
            v *= (1.0f - z);
            v = dv * v + (1.0f - dv) * (buf[j] - ba);
            z = (v >= 1.0f) ? 1.0f : 0.0f;
            ba = db * ba + (1.0f - db) * (be * v + be2 * z);
            any = any || (z != 0.0f);
            curp[(size_t)t * GOUT]     = z;
            vf[(size_t)t * GOUT]       = v;
            zf[(size_t)t * GOUT]       = z;
            bfp[(size_t)t * GOUT]      = ba;
        }
        if (more) {
            #pragma unroll
            for (int j = 0; j < 10; ++j) buf[j] = nxt[j];
        }
    }
    if (any) atomicOr(flag, 1u);
}

// Monolithic fallback scan (used only if ws_size is too small for seeds)
__global__ __launch_bounds__(128) void alif_scan(
    float* __restrict__ out,
    const float* __restrict__ beta, const float* __restrict__ beta2,
    const float* __restrict__ decay_v, const float* __restrict__ decay_b,
    unsigned int* __restrict__ flag)
{
    const int gid = blockIdx.x * 128 + threadIdx.x;
    const int o = gid & (GOUT - 1);
    const int b = gid >> 9;
    const float dv = decay_v[o], db = decay_b[o];
    const float be = beta[o],    be2 = beta2[o];
    float* curp = out + (size_t)b * GT * GOUT + o;
    const size_t SB = (size_t)GB * GT * GOUT;
    const size_t PL = (size_t)GB * (GT + 1) * GOUT;
    float* vf  = out + SB + (size_t)b * (GT + 1) * GOUT + o;
    float* zf  = vf + PL;
    float* bfp = vf + 2 * PL;
    vf[0] = 0.f; zf[0] = 0.f; bfp[0] = 0.f;
    float v = 0.f, z = 0.f, ba = 0.f;
    bool any = false;
    float buf[8];
    #pragma unroll
    for (int j = 0; j < 8; ++j) buf[j] = curp[(size_t)j * GOUT];
    for (int t0 = 0; t0 < GT; t0 += 8) {
        float nxt[8];
        const bool more = (t0 + 8 < GT);
        if (more) {
            #pragma unroll
            for (int j = 0; j < 8; ++j) nxt[j] = curp[(size_t)(t0 + 8 + j) * GOUT];
        }
        #pragma unroll
        for (int j = 0; j < 8; ++j) {
            const int t = t0 + j;
            v *= (1.0f - z);
            v = dv * v + (1.0f - dv) * (buf[j] - ba);
            z = (v >= 1.0f) ? 1.0f : 0.0f;
            ba = db * ba + (1.0f - db) * (be * v + be2 * z);
            any = any || (z != 0.0f);
            curp[(size_t)t * GOUT]      = z;
            vf[(size_t)(t + 1) * GOUT]  = v;
            zf[(size_t)(t + 1) * GOUT]  = z;
            bfp[(size_t)(t + 1) * GOUT] = ba;
        }
        if (more) {
            #pragma unroll
            for (int j = 0; j < 8; ++j) buf[j] = nxt[j];
        }
    }
    if (any) atomicOr(flag, 1u);
}

// Exact fallback with full recurrent coupling (early-exits on flag==0, ~2us)
__global__ __launch_bounds__(512) void alif_exact(
    const float* __restrict__ X, const float* __restrict__ W,
    const float* __restrict__ bias, const float* __restrict__ R,
    const float* __restrict__ beta, const float* __restrict__ beta2,
    const float* __restrict__ decay_v, const float* __restrict__ decay_b,
    float* __restrict__ out, const unsigned int* __restrict__ flag)
{
    if (*flag == 0u) return;
    const int b = blockIdx.x;
    const int o = threadIdx.x;
    __shared__ float xs[GIN];
    __shared__ float zsh[GOUT];
    __shared__ int sflag;
    const float dv = decay_v[o], db = decay_b[o];
    const float be = beta[o],    be2 = beta2[o];
    const float bi = bias[o];
    float* zsp = out + (size_t)b * GT * GOUT + o;
    const size_t SB = (size_t)GB * GT * GOUT, PL = (size_t)GB * (GT + 1) * GOUT;
    float* vf  = out + SB + (size_t)b * (GT + 1) * GOUT + o;
    float* zf  = vf + PL;
    float* bfp = vf + 2 * PL;
    vf[0] = 0.f; zf[0] = 0.f; bfp[0] = 0.f;
    float v = 0.f, z = 0.f, ba = 0.f;
    const float* wr = W + (size_t)o * GIN;
    const float* rr = R + (size_t)o * GOUT;
    for (int t = 0; t < GT; ++t) {
        __syncthreads();
        xs[o]  = X[((size_t)b * GT + t) * GIN + o];
        zsh[o] = z;
        if (o == 0) sflag = 0;
        __syncthreads();
        if (z != 0.f) sflag = 1;
        __syncthreads();
        float cur = bi;
        #pragma unroll 8
        for (int i = 0; i < GIN; ++i) cur += wr[i] * xs[i];
        if (sflag) {
            #pragma unroll 8
            for (int i = 0; i < GOUT; ++i) cur += rr[i] * zsh[i];
        }
        v *= (1.f - z);
        v = dv * v + (1.f - dv) * (cur - ba);
        z = (v >= 1.f) ? 1.f : 0.f;
        ba = db * ba + (1.f - db) * (be * v + be2 * z);
        zsp[(size_t)t * GOUT]       = z;
        vf[(size_t)(t + 1) * GOUT]  = v;
        zf[(size_t)(t + 1) * GOUT]  = z;
        bfp[(size_t)(t + 1) * GOUT] = ba;
    }
}

extern "C" void kernel_launch(void* const* d_in, const int* in_sizes, int n_in,
                              void* d_out, int out_size, void* d_ws, size_t ws_size,
                              hipStream_t stream)
{
    const float* X     = (const float*)d_in[0];
    const float* W     = (const float*)d_in[1];
    const float* bias  = (const float*)d_in[2];
    const float* R     = (const float*)d_in[3];
    const float* beta  = (const float*)d_in[4];
    const float* beta2 = (const float*)d_in[5];
    const float* dv    = (const float*)d_in[6];
    const float* db    = (const float*)d_in[7];
    float* out = (float*)d_out;
    unsigned int* flag = (unsigned int*)d_ws;

    // bf16 W buffer lives in the states region of d_out (overwritten only by
    // pass3/scan, which run strictly after the GEMM on this stream).
    const size_t SB = (size_t)GB * GT * GOUT;
    unsigned short* Wh = (unsigned short*)(out + SB);

    const size_t seeds_b = (size_t)GB * NCH * GOUT * sizeof(float2);  // 5.24 MB
    const size_t need_f  = 256 + seeds_b;
    const size_t need_h  = need_f + (size_t)GM * GOUT * 2;            // +65.5 MB fp16 cur

    alif_cvt_w<<<dim3(NW8 / 256), dim3(256), 0, stream>>>(W, Wh, flag);

    if (ws_size >= need_h) {
        // primary path: fp16 cur in workspace (L3-resident between passes)
        float2* u = (float2*)((char*)d_ws + 256);
        unsigned short* curh = (unsigned short*)((char*)d_ws + need_f);
        alif_gemmf<true><<<dim3(500), dim3(512), 0, stream>>>(X, Wh, bias, nullptr, curh);
        alif_pass1_h<<<dim3(GB * NCH * GOUT / 512), dim3(256), 0, stream>>>(curh, beta, dv, db, u);
        alif_pass2<<<dim3(GB * GOUT / 256), dim3(256), 0, stream>>>(u, beta, dv, db);
        alif_pass3_h<<<dim3(GB * NCH * GOUT / 512), dim3(256), 0, stream>>>(curh, out, u, beta, beta2, dv, db, flag);
    } else if (ws_size >= need_f) {
        // legacy path: fp32 cur in the zs region of d_out
        float2* u = (float2*)((char*)d_ws + 256);
        alif_gemmf<false><<<dim3(500), dim3(512), 0, stream>>>(X, Wh, bias, out, nullptr);
        alif_pass1<<<dim3(GB * NCH * GOUT / 256), dim3(256), 0, stream>>>(out, beta, dv, db, u);
        alif_pass2<<<dim3(GB * GOUT / 256), dim3(256), 0, stream>>>(u, beta, dv, db);
        alif_pass3<<<dim3(GB * NCH * GOUT / 256), dim3(256), 0, stream>>>(out, u, beta, beta2, dv, db, flag);
    } else {
        alif_gemmf<false><<<dim3(500), dim3(512), 0, stream>>>(X, Wh, bias, out, nullptr);
        alif_scan<<<dim3(256), dim3(128), 0, stream>>>(out, beta, beta2, dv, db, flag);
    }
    alif_exact<<<dim3(GB), dim3(512), 0, stream>>>(X, W, bias, R, beta, beta2, dv, db, out, flag);
}